// Round 10
// baseline (57.274 us; speedup 1.0000x reference)
//
#include <hip/hip_runtime.h>
#include <hip/hip_bf16.h>

// SmoothLDDTLoss: b=2, n=4096
// inputs: pred_coords f32[2,4096,3], true_coords f32[2,4096,3],
//         is_dna i32[2,4096], is_rna i32[2,4096], coords_mask i32[2,4096]
// output: scalar f32 = 1 - mean_b(lddt_b)
//
// sigma(.5-d)+sigma(1-d)+sigma(2-d)+sigma(4-d) = t*Q'(t)/Q(t), t=e^{-d} (exact).
// Coords pre-scaled by log2(e) so t = exp2(-|dt_s-dp_s|) is a raw v_exp_f32.
// Symmetry via cyclic half-shell: o=(j-i) mod n, o in [1, n/2], weight 1/2 at
// o==n/2 -> exactly half the i!=j sum for BOTH eps-sum and count.
//
// r9 lesson: all 4 waves swept the SAME o-order in lockstep -> they all stall
// on the same j-line miss simultaneously; wave supply hides nothing.
// Fix: (a) stagger each wave's sweep phase by 8 tiles (mod 33) so the CU has
// 4 independent miss streams; (b) depth-2 prefetch ring (~2 tiles ~ 350 cyc
// slack > L2 latency). Keep deep blocks (r5/r8 showed shallow blocks = 73us)
// and (256,6) launch bounds ((256,8) spilled in r7).

#define NRES 4096
#define NBATCH 2
#define TI 8
#define NTW 33             // wave-tiles of 64 lanes: o in [0, 2112)
#define NBLOCKS 1024       // 512 strips * 2 batches

// scaled cutoffs: 15*log2(e), 30*log2(e)
#define CUT15 21.6404256133f
#define CUT30 43.2808512267f

// Q coefficients: elementary symmetric polys of {e^0.5, e^1, e^2, e^4}
#define S1 66.35420923f
#define S2 678.60880385f
#define S3 2039.58217570f
#define S4 1808.04241445f
// Q'(t)/4 coefficients
#define QP1 16.58855231f
#define QP2 339.30440193f
#define QP3 1529.68663177f
#define QP4 1808.04241445f

#define LOG2E 1.44269504089f

__global__ void pack_kernel(const float* __restrict__ pred,
                            const float* __restrict__ truec,
                            const int* __restrict__ dna,
                            const int* __restrict__ rna,
                            const int* __restrict__ cm,
                            float4* __restrict__ tp,
                            float4* __restrict__ pp)
{
    int idx = blockIdx.x * 256 + threadIdx.x;
    if (idx >= NRES * NBATCH) return;
    float nuc = ((dna[idx] | rna[idx]) != 0) ? 1.0f : 0.0f;
    float cmf = (cm[idx] != 0) ? 1.0f : 0.0f;
    tp[idx] = make_float4(truec[3*idx+0]*LOG2E, truec[3*idx+1]*LOG2E, truec[3*idx+2]*LOG2E, nuc);
    pp[idx] = make_float4(pred[3*idx+0]*LOG2E,  pred[3*idx+1]*LOG2E,  pred[3*idx+2]*LOG2E,  cmf);
}

// one pair eval for one strip row; MODE 0: interior tile, 1: lower edge
// (need o > r), 2: upper edge (need o-r <= 2048, half weight at == 2048)
#define EVAL_ROW(TX,TY,TZ,PX,PY,PZ,CHI,CLO,RREL,MODE)                       \
    {                                                                       \
        float dx = TX - tc.x, dy = TY - tc.y, dz = TZ - tc.z;               \
        float dt = __builtin_amdgcn_sqrtf(dx*dx + dy*dy + dz*dz);           \
        float ex = PX - pc.x, ey = PY - pc.y, ez = PZ - pc.z;               \
        float dp = __builtin_amdgcn_sqrtf(ex*ex + ey*ey + ez*ez);           \
        float cutoff = nucj ? CHI : CLO;                                    \
        float mf = (dt < cutoff) ? wj : 0.0f;                               \
        if (MODE == 1) mf = (o > RREL) ? mf : 0.0f;                         \
        if (MODE == 2) { int d = o - RREL;                                  \
            mf = (d <= 2048) ? mf : 0.0f;                                   \
            mf = (d == 2048) ? 0.5f * mf : mf; }                            \
        float t = __builtin_amdgcn_exp2f(-fabsf(dt - dp));                  \
        float Q  = 1.0f + t*(S1 + t*(S2 + t*(S3 + t*S4)));                  \
        float Qp = QP1 + t*(QP2 + t*(QP3 + t*QP4));                         \
        float rq = __builtin_amdgcn_rcpf(Q);                                \
        s += mf * ((t * Qp) * rq);                                          \
        c += mf;                                                            \
    }

#define TILE_BODY(MODE)                                                     \
    EVAL_ROW(tAx,tAy,tAz,pAx,pAy,pAz,cHiA,cLoA,rA,MODE)                     \
    EVAL_ROW(tBx,tBy,tBz,pBx,pBy,pBz,cHiB,cLoB,rB,MODE)

__launch_bounds__(256, 6)
__global__ void lddt_main(const float4* __restrict__ tp,
                          const float4* __restrict__ pp,
                          float* __restrict__ acc,          // [0..1] sums, [2..3] counts
                          unsigned int* __restrict__ done,  // block-completion counter
                          float* __restrict__ out)
{
    const int b    = blockIdx.y;
    const int i0   = blockIdx.x * TI;
    const int base = b * NRES;
    const int tid  = threadIdx.x;
    // wave id as a provably-uniform scalar (enables SGPR rows + scalar branches)
    const int wid  = __builtin_amdgcn_readfirstlane(tid >> 6);
    const int lane = tid & 63;

    // this wave's two strip rows (relative indices rA=2w, rB=2w+1)
    const int rA = 2 * wid;
    const int rB = rA + 1;

    float4 tA4 = tp[base + i0 + rA];
    float4 pA4 = pp[base + i0 + rA];
    float4 tB4 = tp[base + i0 + rB];
    float4 pB4 = pp[base + i0 + rB];

    const float tAx = tA4.x, tAy = tA4.y, tAz = tA4.z;
    const float pAx = pA4.x, pAy = pA4.y, pAz = pA4.z;
    const float tBx = tB4.x, tBy = tB4.y, tBz = tB4.z;
    const float pBx = pB4.x, pBy = pB4.y, pBz = pB4.z;

    const bool cmA  = (pA4.w != 0.0f), nucA = (tA4.w != 0.0f);
    const bool cmB  = (pB4.w != 0.0f), nucB = (tB4.w != 0.0f);
    const float cHiA = cmA ? (nucA ? CUT30 : CUT15) : -1.0f;
    const float cLoA = cmA ? CUT15 : -1.0f;
    const float cHiB = cmB ? (nucB ? CUT30 : CUT15) : -1.0f;
    const float cLoB = cmB ? CUT15 : -1.0f;

    float s = 0.0f, c = 0.0f;

    // staggered sweep: wave w starts at tile 8w (mod 33) -> 4 independent
    // miss streams per block instead of 4 waves queueing on the same line
    const int start = wid * 8;

    int t1 = start + 1; if (t1 >= NTW) t1 -= NTW;
    float4 tc = tp[base + ((i0 + (start << 6) + lane) & (NRES - 1))];
    float4 pc = pp[base + ((i0 + (start << 6) + lane) & (NRES - 1))];
    float4 tn = tp[base + ((i0 + (t1 << 6) + lane) & (NRES - 1))];
    float4 pn = pp[base + ((i0 + (t1 << 6) + lane) & (NRES - 1))];

    #pragma unroll 1
    for (int k = 0; k < NTW; ++k) {
        int tl = start + k;      if (tl  >= NTW) tl  -= NTW;
        int tl2 = start + k + 2; if (tl2 >= NTW) tl2 -= NTW;
        // (start+k+2 <= 58 < 2*NTW, one subtract suffices)

        // depth-2 prefetch (last iters re-fetch visited tiles; L1-hot, harmless)
        const int jf = base + ((i0 + (tl2 << 6) + lane) & (NRES - 1));
        float4 tf = tp[jf];
        float4 pf = pp[jf];

        const float wj   = pc.w;              // cm_j as 1.0/0.0
        const bool  nucj = (tc.w != 0.0f);
        const int   o    = (tl << 6) + lane;  // cyclic offset j-i0

        if (tl == 0)            { TILE_BODY(1) }
        else if (tl == NTW - 1) { TILE_BODY(2) }
        else                    { TILE_BODY(0) }

        tc = tn; pc = pn; tn = tf; pn = pf;
    }

    // wave (64-lane) reduction
    #pragma unroll
    for (int off = 32; off > 0; off >>= 1) {
        s += __shfl_down(s, off, 64);
        c += __shfl_down(c, off, 64);
    }

    __shared__ float red_s[4];
    __shared__ float red_c[4];
    if (lane == 0) { red_s[wid] = s; red_c[wid] = c; }
    __syncthreads();

    if (tid == 0) {
        float ts = red_s[0] + red_s[1] + red_s[2] + red_s[3];
        float tc2 = red_c[0] + red_c[1] + red_c[2] + red_c[3];
        atomicAdd(&acc[b], ts);
        atomicAdd(&acc[NBATCH + b], tc2);
        __threadfence();
        unsigned int old = atomicAdd(done, 1u);
        if (old == NBLOCKS - 1u) {
            float a0 = __hip_atomic_load(&acc[0], __ATOMIC_ACQUIRE, __HIP_MEMORY_SCOPE_AGENT);
            float a1 = __hip_atomic_load(&acc[1], __ATOMIC_ACQUIRE, __HIP_MEMORY_SCOPE_AGENT);
            float c0 = __hip_atomic_load(&acc[2], __ATOMIC_ACQUIRE, __HIP_MEMORY_SCOPE_AGENT);
            float c1 = __hip_atomic_load(&acc[3], __ATOMIC_ACQUIRE, __HIP_MEMORY_SCOPE_AGENT);
            float l0 = a0 / fmaxf(c0, 0.5f);
            float l1 = a1 / fmaxf(c1, 0.5f);
            out[0] = 1.0f - 0.5f * (l0 + l1);
        }
    }
}

extern "C" void kernel_launch(void* const* d_in, const int* in_sizes, int n_in,
                              void* d_out, int out_size, void* d_ws, size_t ws_size,
                              hipStream_t stream) {
    const float* pred  = (const float*)d_in[0];
    const float* truec = (const float*)d_in[1];
    const int*   dna   = (const int*)d_in[2];
    const int*   rna   = (const int*)d_in[3];
    const int*   cmask = (const int*)d_in[4];
    float* out = (float*)d_out;

    char* ws = (char*)d_ws;
    float*        acc  = (float*)ws;              // 4 floats
    unsigned int* done = (unsigned int*)(ws + 64);
    float4* tp = (float4*)(ws + 1024);            // 2*4096*16 B
    float4* pp = (float4*)(ws + 1024 + NBATCH*NRES*16);

    (void)hipMemsetAsync(ws, 0, 128, stream);     // acc + done

    pack_kernel<<<(NRES*NBATCH + 255)/256, 256, 0, stream>>>(pred, truec, dna, rna, cmask, tp, pp);

    dim3 grid(NRES / TI, NBATCH);
    lddt_main<<<grid, 256, 0, stream>>>(tp, pp, acc, done, out);
}

// Round 11
// 53.931 us; speedup vs baseline: 1.0620x; 1.0620x over previous
//
#include <hip/hip_runtime.h>
#include <hip/hip_bf16.h>

// SmoothLDDTLoss: b=2, n=4096
// inputs: pred_coords f32[2,4096,3], true_coords f32[2,4096,3],
//         is_dna i32[2,4096], is_rna i32[2,4096], coords_mask i32[2,4096]
// output: scalar f32 = 1 - mean_b(lddt_b)
//
// sigma(.5-d)+sigma(1-d)+sigma(2-d)+sigma(4-d) = t*Q'(t)/Q(t), t=e^{-d} (exact).
// Coords pre-scaled by log2(e) so t = exp2(-|dt_s-dp_s|) is a raw v_exp_f32.
//
// r10 lesson: per-wave j-streams oversubscribe the CU's L1 port (each wave
// privately pulls 32 B/pair); no amount of prefetch/stagger helps a full pipe.
// This version: N-body LDS broadcast. Each thread owns ONE i (registers);
// block stages a 128-j chunk in LDS once; inner loop reads each j at a
// wave-uniform LDS address (conflict-free broadcast) -> 0.5 B/pair.
// Full-sum rectangles (no triangle tricks): every block is a clean 256x128
// tile, no edge predicates. Diagonal subtracted analytically via per-batch
// valid-row counts (computed in pack). Finalize fused via done-counter.

#define NRES 4096
#define NBATCH 2
#define TJ 128                      // j-chunk per block
#define NBLOCKS (16 * 32 * NBATCH)  // (4096/256) i-blocks * (4096/128) j-chunks * b

// scaled cutoffs: 15*log2(e), 30*log2(e)
#define CUT15 21.6404256133f
#define CUT30 43.2808512267f

// Q coefficients: elementary symmetric polys of {e^0.5, e^1, e^2, e^4}
#define S1 66.35420923f
#define S2 678.60880385f
#define S3 2039.58217570f
#define S4 1808.04241445f
// Q'(t)/4 coefficients
#define QP1 16.58855231f
#define QP2 339.30440193f
#define QP3 1529.68663177f
#define QP4 1808.04241445f

// eps of a diagonal pair (diff=0): (sig(.5)+sig(1)+sig(2)+sig(4))/4
#define DIAG_EPS 0.80408219445f
#define LOG2E 1.44269504089f

__global__ void pack_kernel(const float* __restrict__ pred,
                            const float* __restrict__ truec,
                            const int* __restrict__ dna,
                            const int* __restrict__ rna,
                            const int* __restrict__ cm,
                            float4* __restrict__ tp,
                            float4* __restrict__ pp,
                            float* __restrict__ acc)
{
    int idx = blockIdx.x * 256 + threadIdx.x;
    if (idx >= NRES * NBATCH) return;
    float nuc = ((dna[idx] | rna[idx]) != 0) ? 1.0f : 0.0f;
    float cmf = (cm[idx] != 0) ? 1.0f : 0.0f;
    tp[idx] = make_float4(truec[3*idx+0]*LOG2E, truec[3*idx+1]*LOG2E, truec[3*idx+2]*LOG2E, nuc);
    pp[idx] = make_float4(pred[3*idx+0]*LOG2E,  pred[3*idx+1]*LOG2E,  pred[3*idx+2]*LOG2E,  cmf);

    // per-batch valid-row count for the diagonal correction
    // (waves never straddle a batch boundary: 4096 % 64 == 0)
    float v = cmf;
    #pragma unroll
    for (int o = 32; o > 0; o >>= 1) v += __shfl_down(v, o, 64);
    if ((threadIdx.x & 63) == 0) atomicAdd(&acc[4 + (idx >> 12)], v);
}

__launch_bounds__(256, 4)
__global__ void lddt_main(const float4* __restrict__ tp,
                          const float4* __restrict__ pp,
                          float* __restrict__ acc,          // [0..1] sums, [2..3] cnts, [4..5] rows
                          unsigned int* __restrict__ done,
                          float* __restrict__ out)
{
    const int b    = blockIdx.z;
    const int j0   = blockIdx.y * TJ;
    const int i    = blockIdx.x * 256 + threadIdx.x;   // this thread's i
    const int base = b * NRES;
    const int tid  = threadIdx.x;

    __shared__ float4 stj[TJ];
    __shared__ float4 spj[TJ];

    // stage the j-chunk once per block (256 threads, 256 float4 loads total)
    if (tid < TJ) stj[tid]      = tp[base + j0 + tid];
    else          spj[tid - TJ] = pp[base + j0 + (tid - TJ)];

    // this thread's i-data (coalesced 16B loads)
    const float4 ti4 = tp[base + i];
    const float4 pi4 = pp[base + i];
    const float tix = ti4.x, tiy = ti4.y, tiz = ti4.z;
    const float pix = pi4.x, piy = pi4.y, piz = pi4.z;
    const bool  cmi  = (pi4.w != 0.0f);
    const bool  nuci = (ti4.w != 0.0f);
    // cm_i folded into cutoffs: masked row -> cutoff -1 -> never included
    const float cHi = cmi ? (nuci ? CUT30 : CUT15) : -1.0f;
    const float cLo = cmi ? CUT15 : -1.0f;

    __syncthreads();

    float s = 0.0f, c = 0.0f;

    #pragma unroll 4
    for (int k = 0; k < TJ; ++k) {
        // wave-uniform address -> conflict-free LDS broadcast
        const float4 tj = stj[k];
        const float4 pj = spj[k];

        float dx = tix - tj.x, dy = tiy - tj.y, dz = tiz - tj.z;
        float dt = __builtin_amdgcn_sqrtf(dx*dx + dy*dy + dz*dz);
        float ex = pix - pj.x, ey = piy - pj.y, ez = piz - pj.z;
        float dp = __builtin_amdgcn_sqrtf(ex*ex + ey*ey + ez*ez);

        float cutoff = (tj.w != 0.0f) ? cHi : cLo;
        float mf = (dt < cutoff) ? pj.w : 0.0f;    // pj.w = cm_j (diag kept, fixed later)

        float t = __builtin_amdgcn_exp2f(-fabsf(dt - dp));   // v_exp_f32, -abs mod
        float Q  = 1.0f + t*(S1 + t*(S2 + t*(S3 + t*S4)));
        float Qp = QP1 + t*(QP2 + t*(QP3 + t*QP4));          // Q'(t)/4
        float rq = __builtin_amdgcn_rcpf(Q);

        s += mf * ((t * Qp) * rq);
        c += mf;
    }

    // wave (64-lane) reduction
    #pragma unroll
    for (int off = 32; off > 0; off >>= 1) {
        s += __shfl_down(s, off, 64);
        c += __shfl_down(c, off, 64);
    }

    __shared__ float red_s[4];
    __shared__ float red_c[4];
    const int wid  = tid >> 6;
    const int lane = tid & 63;
    if (lane == 0) { red_s[wid] = s; red_c[wid] = c; }
    __syncthreads();

    if (tid == 0) {
        float ts = red_s[0] + red_s[1] + red_s[2] + red_s[3];
        float tc = red_c[0] + red_c[1] + red_c[2] + red_c[3];
        atomicAdd(&acc[b], ts);
        atomicAdd(&acc[NBATCH + b], tc);
        __threadfence();
        unsigned int old = atomicAdd(done, 1u);
        if (old == NBLOCKS - 1u) {
            float a0 = __hip_atomic_load(&acc[0], __ATOMIC_ACQUIRE, __HIP_MEMORY_SCOPE_AGENT);
            float a1 = __hip_atomic_load(&acc[1], __ATOMIC_ACQUIRE, __HIP_MEMORY_SCOPE_AGENT);
            float c0 = __hip_atomic_load(&acc[2], __ATOMIC_ACQUIRE, __HIP_MEMORY_SCOPE_AGENT);
            float c1 = __hip_atomic_load(&acc[3], __ATOMIC_ACQUIRE, __HIP_MEMORY_SCOPE_AGENT);
            float M0 = __hip_atomic_load(&acc[4], __ATOMIC_ACQUIRE, __HIP_MEMORY_SCOPE_AGENT);
            float M1 = __hip_atomic_load(&acc[5], __ATOMIC_ACQUIRE, __HIP_MEMORY_SCOPE_AGENT);
            // remove diagonal (each valid row contributed eps=DIAG_EPS, count=1)
            float l0 = (a0 - DIAG_EPS * M0) / fmaxf(c0 - M0, 1.0f);
            float l1 = (a1 - DIAG_EPS * M1) / fmaxf(c1 - M1, 1.0f);
            out[0] = 1.0f - 0.5f * (l0 + l1);
        }
    }
}

extern "C" void kernel_launch(void* const* d_in, const int* in_sizes, int n_in,
                              void* d_out, int out_size, void* d_ws, size_t ws_size,
                              hipStream_t stream) {
    const float* pred  = (const float*)d_in[0];
    const float* truec = (const float*)d_in[1];
    const int*   dna   = (const int*)d_in[2];
    const int*   rna   = (const int*)d_in[3];
    const int*   cmask = (const int*)d_in[4];
    float* out = (float*)d_out;

    char* ws = (char*)d_ws;
    float*        acc  = (float*)ws;              // 6 floats used
    unsigned int* done = (unsigned int*)(ws + 64);
    float4* tp = (float4*)(ws + 1024);            // 2*4096*16 B
    float4* pp = (float4*)(ws + 1024 + NBATCH*NRES*16);

    (void)hipMemsetAsync(ws, 0, 128, stream);     // acc + done

    pack_kernel<<<(NRES*NBATCH + 255)/256, 256, 0, stream>>>(pred, truec, dna, rna, cmask, tp, pp, acc);

    dim3 grid(NRES / 256, NRES / TJ, NBATCH);
    lddt_main<<<grid, 256, 0, stream>>>(tp, pp, acc, done, out);
}

// Round 12
// 50.342 us; speedup vs baseline: 1.1377x; 1.0713x over previous
//
#include <hip/hip_runtime.h>
#include <hip/hip_bf16.h>

// SmoothLDDTLoss: b=2, n=4096
// inputs: pred_coords f32[2,4096,3], true_coords f32[2,4096,3],
//         is_dna i32[2,4096], is_rna i32[2,4096], coords_mask i32[2,4096]
// output: scalar f32 = 1 - mean_b(lddt_b)
//
// sigma(.5-d)+sigma(1-d)+sigma(2-d)+sigma(4-d) = t*Q'(t)/Q(t), t=e^{-d} (exact).
// Coords pre-scaled by log2(e) so t = exp2(-|dt_s-dp_s|) is a raw v_exp_f32.
//
// Structure (r11): each thread owns one i (registers); block stages a 128-j
// chunk in LDS once; inner loop is a conflict-free LDS broadcast (0.5 B/pair).
// r12: upper-triangle only (j>i; symmetric terms, 2x cancels in s/c). Active
// blocks keep the identical 256i x 128j shape; tiles fully below the diagonal
// early-return (cheap); only the 2 diagonal-straddling tiles per i-block run
// the j>i predicate (wave-uniform branch). Diagonal excluded by strict j>i.
// r5's triangle failed for block-shape reasons (shallow per-block work +
// heavy prologue); here the prologue is 2 loads/thread and active tiles are
// uniform, so only the pair count changes (33.5M -> 17.5M).

#define NRES 4096
#define NBATCH 2
#define TJ 128
#define NBLOCKS (16 * 32 * NBATCH)   // dispatched blocks (incl. early-exit ones)

// scaled cutoffs: 15*log2(e), 30*log2(e)
#define CUT15 21.6404256133f
#define CUT30 43.2808512267f

// Q coefficients: elementary symmetric polys of {e^0.5, e^1, e^2, e^4}
#define S1 66.35420923f
#define S2 678.60880385f
#define S3 2039.58217570f
#define S4 1808.04241445f
// Q'(t)/4 coefficients
#define QP1 16.58855231f
#define QP2 339.30440193f
#define QP3 1529.68663177f
#define QP4 1808.04241445f

#define LOG2E 1.44269504089f

__global__ void pack_kernel(const float* __restrict__ pred,
                            const float* __restrict__ truec,
                            const int* __restrict__ dna,
                            const int* __restrict__ rna,
                            const int* __restrict__ cm,
                            float4* __restrict__ tp,
                            float4* __restrict__ pp)
{
    int idx = blockIdx.x * 256 + threadIdx.x;
    if (idx >= NRES * NBATCH) return;
    float nuc = ((dna[idx] | rna[idx]) != 0) ? 1.0f : 0.0f;
    float cmf = (cm[idx] != 0) ? 1.0f : 0.0f;
    tp[idx] = make_float4(truec[3*idx+0]*LOG2E, truec[3*idx+1]*LOG2E, truec[3*idx+2]*LOG2E, nuc);
    pp[idx] = make_float4(pred[3*idx+0]*LOG2E,  pred[3*idx+1]*LOG2E,  pred[3*idx+2]*LOG2E,  cmf);
}

// DIAG=0: interior tile (all j>i guaranteed); DIAG=1: add strict j>i predicate
#define K_LOOP(DIAG)                                                        \
    _Pragma("unroll 4")                                                     \
    for (int k = 0; k < TJ; ++k) {                                          \
        const float4 tj = stj[k];                                           \
        const float4 pj = spj[k];                                           \
        float dx = tix - tj.x, dy = tiy - tj.y, dz = tiz - tj.z;            \
        float dt = __builtin_amdgcn_sqrtf(dx*dx + dy*dy + dz*dz);           \
        float ex = pix - pj.x, ey = piy - pj.y, ez = piz - pj.z;            \
        float dp = __builtin_amdgcn_sqrtf(ex*ex + ey*ey + ez*ez);           \
        float cutoff = __builtin_fmaf(tj.w, cHiLo, cLo);                    \
        float mf = (dt < cutoff) ? pj.w : 0.0f;                             \
        if (DIAG) mf = (j0 + k > i) ? mf : 0.0f;                            \
        float t = __builtin_amdgcn_exp2f(-fabsf(dt - dp));                  \
        float Q  = 1.0f + t*(S1 + t*(S2 + t*(S3 + t*S4)));                  \
        float Qp = QP1 + t*(QP2 + t*(QP3 + t*QP4));                         \
        float rq = __builtin_amdgcn_rcpf(Q);                                \
        s += mf * ((t * Qp) * rq);                                          \
        c += mf;                                                            \
    }

__launch_bounds__(256, 4)
__global__ void lddt_main(const float4* __restrict__ tp,
                          const float4* __restrict__ pp,
                          float* __restrict__ acc,          // [0..1] sums, [2..3] counts
                          unsigned int* __restrict__ done,
                          float* __restrict__ out)
{
    const int b   = blockIdx.z;
    const int bi  = blockIdx.x;          // i-block (256 rows at 256*bi)
    const int cj  = blockIdx.y;          // j-chunk (128 cols at 128*cj)
    const int tid = threadIdx.x;

    // below-diagonal tile: all pairs have j < i -> covered by symmetry
    if (cj < 2 * bi) {
        if (tid == 0) {
            __threadfence();
            unsigned int old = atomicAdd(done, 1u);
            if (old == NBLOCKS - 1u) {
                float a0 = __hip_atomic_load(&acc[0], __ATOMIC_ACQUIRE, __HIP_MEMORY_SCOPE_AGENT);
                float a1 = __hip_atomic_load(&acc[1], __ATOMIC_ACQUIRE, __HIP_MEMORY_SCOPE_AGENT);
                float c0 = __hip_atomic_load(&acc[2], __ATOMIC_ACQUIRE, __HIP_MEMORY_SCOPE_AGENT);
                float c1 = __hip_atomic_load(&acc[3], __ATOMIC_ACQUIRE, __HIP_MEMORY_SCOPE_AGENT);
                float l0 = a0 / fmaxf(c0, 0.5f);
                float l1 = a1 / fmaxf(c1, 0.5f);
                out[0] = 1.0f - 0.5f * (l0 + l1);
            }
        }
        return;
    }

    const int base = b * NRES;
    const int j0   = cj * TJ;
    const int i    = bi * 256 + tid;

    __shared__ float4 stj[TJ];
    __shared__ float4 spj[TJ];
    if (tid < TJ) stj[tid]      = tp[base + j0 + tid];
    else          spj[tid - TJ] = pp[base + j0 + (tid - TJ)];

    const float4 ti4 = tp[base + i];
    const float4 pi4 = pp[base + i];
    const float tix = ti4.x, tiy = ti4.y, tiz = ti4.z;
    const float pix = pi4.x, piy = pi4.y, piz = pi4.z;
    const bool  cmi  = (pi4.w != 0.0f);
    const bool  nuci = (ti4.w != 0.0f);
    const float cHi = cmi ? (nuci ? CUT30 : CUT15) : -1.0f;
    const float cLo = cmi ? CUT15 : -1.0f;
    const float cHiLo = cHi - cLo;       // cutoff = fma(nucj, cHiLo, cLo)

    __syncthreads();

    float s = 0.0f, c = 0.0f;

    if (cj <= 2 * bi + 1) { K_LOOP(1) }  // diagonal-straddling tile
    else                  { K_LOOP(0) }  // interior tile (j > i always)

    // wave (64-lane) reduction
    #pragma unroll
    for (int off = 32; off > 0; off >>= 1) {
        s += __shfl_down(s, off, 64);
        c += __shfl_down(c, off, 64);
    }

    __shared__ float red_s[4];
    __shared__ float red_c[4];
    const int wid  = tid >> 6;
    const int lane = tid & 63;
    if (lane == 0) { red_s[wid] = s; red_c[wid] = c; }
    __syncthreads();

    if (tid == 0) {
        float ts = red_s[0] + red_s[1] + red_s[2] + red_s[3];
        float tc = red_c[0] + red_c[1] + red_c[2] + red_c[3];
        atomicAdd(&acc[b], ts);
        atomicAdd(&acc[NBATCH + b], tc);
        __threadfence();
        unsigned int old = atomicAdd(done, 1u);
        if (old == NBLOCKS - 1u) {
            float a0 = __hip_atomic_load(&acc[0], __ATOMIC_ACQUIRE, __HIP_MEMORY_SCOPE_AGENT);
            float a1 = __hip_atomic_load(&acc[1], __ATOMIC_ACQUIRE, __HIP_MEMORY_SCOPE_AGENT);
            float c0 = __hip_atomic_load(&acc[2], __ATOMIC_ACQUIRE, __HIP_MEMORY_SCOPE_AGENT);
            float c1 = __hip_atomic_load(&acc[3], __ATOMIC_ACQUIRE, __HIP_MEMORY_SCOPE_AGENT);
            float l0 = a0 / fmaxf(c0, 0.5f);
            float l1 = a1 / fmaxf(c1, 0.5f);
            out[0] = 1.0f - 0.5f * (l0 + l1);
        }
    }
}

extern "C" void kernel_launch(void* const* d_in, const int* in_sizes, int n_in,
                              void* d_out, int out_size, void* d_ws, size_t ws_size,
                              hipStream_t stream) {
    const float* pred  = (const float*)d_in[0];
    const float* truec = (const float*)d_in[1];
    const int*   dna   = (const int*)d_in[2];
    const int*   rna   = (const int*)d_in[3];
    const int*   cmask = (const int*)d_in[4];
    float* out = (float*)d_out;

    char* ws = (char*)d_ws;
    float*        acc  = (float*)ws;              // 4 floats
    unsigned int* done = (unsigned int*)(ws + 64);
    float4* tp = (float4*)(ws + 1024);            // 2*4096*16 B
    float4* pp = (float4*)(ws + 1024 + NBATCH*NRES*16);

    (void)hipMemsetAsync(ws, 0, 128, stream);     // acc + done

    pack_kernel<<<(NRES*NBATCH + 255)/256, 256, 0, stream>>>(pred, truec, dna, rna, cmask, tp, pp);

    dim3 grid(NRES / 256, NRES / TJ, NBATCH);
    lddt_main<<<grid, 256, 0, stream>>>(tp, pp, acc, done, out);
}